// Round 17
// baseline (68.584 us; speedup 1.0000x reference)
//
#include <hip/hip_runtime.h>
#include <math.h>

#define B_     8192
#define LATENT 32
#define CIN    128
#define HID    256
#define ACTD   16
#define NE     8
#define GH     128
#define IN0    160   // LATENT + CIN
#define INTER  288   // HID + LATENT

typedef __attribute__((ext_vector_type(8))) _Float16 half8;
typedef __attribute__((ext_vector_type(4))) float    f32x4;
typedef __attribute__((ext_vector_type(4))) int      i32x4;

__device__ __forceinline__ float elu1(float x) { return x > 0.0f ? x : expm1f(x); }

__device__ __forceinline__ void gload16(const void* g, const char* lds) {
    __builtin_amdgcn_global_load_lds((const __attribute__((address_space(1))) void*)g,
                                     (__attribute__((address_space(3))) void*)lds, 16, 0, 0);
}
__device__ __forceinline__ half8 as_h8(i32x4 v) {
    union U { i32x4 a; half8 b; } u; u.a = v; return u.b;
}

// ---------- fused prep (weight transpose+fp16) and LayerNorm/concat ----------
__global__ __launch_bounds__(256) void k_prep_ln(
    const float* __restrict__ w0, const float* __restrict__ w1, const float* __restrict__ w2,
    const float* __restrict__ g0w, const float* __restrict__ g1w,
    const float* __restrict__ z, const float* __restrict__ c,
    const float* __restrict__ g, const float* __restrict__ bt,
    _Float16* __restrict__ T0, _Float16* __restrict__ T1, _Float16* __restrict__ T2,
    _Float16* __restrict__ G0, _Float16* __restrict__ G1,
    _Float16* __restrict__ X0, _Float16* __restrict__ X1, _Float16* __restrict__ X2)
{
    if (blockIdx.x < 484) {
        int gq = blockIdx.x * 256 + threadIdx.x;
        const float* src; int stride; size_t dst; _Float16* H;
        if (gq < 40960) {                      // T0: [8][160][256] -> [8*256][160]
            int e = gq / 5120, r = gq % 5120, o = r / 20, i0 = (r % 20) * 8;
            src = w0 + ((size_t)e * 160 + i0) * 256 + o; stride = 256;
            dst = ((size_t)e * 256 + o) * 160 + i0; H = T0;
        } else if (gq < 114688) {              // T1
            int t = gq - 40960;
            int e = t / 9216, r = t % 9216, o = r / 36, i0 = (r % 36) * 8;
            src = w1 + ((size_t)e * 288 + i0) * 256 + o; stride = 256;
            dst = ((size_t)e * 256 + o) * 288 + i0; H = T1;
        } else if (gq < 119296) {              // T2
            int t = gq - 114688;
            int e = t / 576, r = t % 576, o = r / 36, i0 = (r % 36) * 8;
            src = w2 + ((size_t)e * 288 + i0) * 16 + o; stride = 16;
            dst = ((size_t)e * 16 + o) * 288 + i0; H = T2;
        } else if (gq < 121856) {              // G0
            int t = gq - 119296;
            int o = t / 20, i0 = (t % 20) * 8;
            src = g0w + (size_t)i0 * 128 + o; stride = 128;
            dst = (size_t)o * 160 + i0; H = G0;
        } else if (gq < 123904) {              // G1
            int t = gq - 121856;
            int o = t / 16, i0 = (t % 16) * 8;
            src = g1w + (size_t)i0 * 128 + o; stride = 128;
            dst = (size_t)o * 128 + i0; H = G1;
        } else return;
        _Float16 hh[8];
        #pragma unroll
        for (int j = 0; j < 8; ++j) hh[j] = (_Float16)src[(size_t)j * stride];
        *(half8*)&H[dst] = *(const half8*)hh;
        return;
    }
    // ---- LayerNorm branch ----
    int gid = (blockIdx.x - 484) * 256 + threadIdx.x;
    int row = gid >> 6;
    int l = threadIdx.x & 63;
    const float* cr = c + (size_t)row * CIN;
    float v0 = cr[l], v1 = cr[l + 64];
    float s = v0 + v1;
    #pragma unroll
    for (int o = 32; o; o >>= 1) s += __shfl_xor(s, o);
    float mean = s * (1.0f / 128.0f);
    float d0 = v0 - mean, d1 = v1 - mean;
    float q = d0 * d0 + d1 * d1;
    #pragma unroll
    for (int o = 32; o; o >>= 1) q += __shfl_xor(q, o);
    float rstd = rsqrtf(q * (1.0f / 128.0f) + 1e-5f);
    float y0 = d0 * rstd * g[l] + bt[l];
    float y1 = d1 * rstd * g[l + 64] + bt[l + 64];
    size_t r0 = (size_t)row * IN0;
    X0[r0 + 32 + l] = (_Float16)y0;
    X0[r0 + 96 + l] = (_Float16)y1;
    if (l < LATENT) {
        _Float16 zv = (_Float16)z[(size_t)row * LATENT + l];
        X0[r0 + l] = zv;
        size_t r1 = (size_t)row * INTER;
        X1[r1 + l] = zv;
        X2[r1 + l] = zv;
    }
}

// ---------- fused gate MLP: both weight stages issued up-front (no mid stall) ----------
__global__ __launch_bounds__(128, 2) void k_gate_fused(
    const _Float16* __restrict__ X0, const _Float16* __restrict__ G0T,
    const _Float16* __restrict__ G1T,
    const float* __restrict__ g0b, const float* __restrict__ g1b,
    const float* __restrict__ g2w, const float* __restrict__ g2b,
    float* __restrict__ coeff)
{
    __shared__ __align__(16) char smem[86016];   // G0 40KB | G1 32KB | h1 8KB | wt_t 4KB
    const int tid = threadIdx.x, wid = tid >> 6, l = tid & 63;
    const int brow = blockIdx.x * 32;
    const int rl16 = wid * 16;

    char* sG1  = smem + 40960;
    char* h1   = smem + 73728;                   // [32 rows][256 B]
    float* wt_t = (float*)(smem + 81920);        // [8][128] f32

    const int swz = (((l & 3) ^ ((l >> 3) & 3)) << 3);
    const int rq  = l >> 2;
    const int rdo = ((l & 15) << 6) + (((l >> 4) ^ ((l >> 1) & 3)) << 4);

    #pragma unroll
    for (int p = 0; p < 40; ++p) {
        if ((p & 1) != wid) continue;
        const int ks = p / 8, gg = p % 8;
        gload16(G0T + (size_t)(gg * 16 + rq) * IN0 + ks * 32 + swz, smem + p * 1024);
    }
    #pragma unroll
    for (int p = 0; p < 32; ++p) {
        if ((p & 1) != wid) continue;
        const int ks = p / 8, gg = p % 8;
        gload16(G1T + (size_t)(gg * 16 + rq) * GH + ks * 32 + swz, sG1 + p * 1024);
    }
    const _Float16* Ar0 = X0 + (size_t)(brow + rl16 + (l & 15)) * IN0 + (l >> 4) * 8;
    i32x4 a0[5];
    #pragma unroll
    for (int ks = 0; ks < 5; ++ks) a0[ks] = *(const i32x4*)(Ar0 + ks * 32);
    for (int idx = tid; idx < 1024; idx += 128)
        wt_t[(idx & 7) * 128 + (idx >> 3)] = g2w[(idx >> 3) * 8 + (idx & 7)];
    __syncthreads();   // full drain: everything staged

    f32x4 acc[8];
    #pragma unroll
    for (int nf = 0; nf < 8; ++nf) {
        float bv = g0b[nf * 16 + (l & 15)];
        acc[nf] = (f32x4){bv, bv, bv, bv};
    }
    #pragma unroll
    for (int ks = 0; ks < 5; ++ks)
        #pragma unroll
        for (int nf = 0; nf < 8; ++nf) {
            half8 b = *(const half8*)(smem + (size_t)(ks * 8 + nf) * 1024 + rdo);
            acc[nf] = __builtin_amdgcn_mfma_f32_16x16x32_f16(as_h8(a0[ks]), b, acc[nf], 0, 0, 0);
        }

    #pragma unroll
    for (int nf = 0; nf < 8; ++nf)
        #pragma unroll
        for (int r = 0; r < 4; ++r) {
            const int rloc = ((l >> 4) << 2) + r;
            const int row = rl16 + rloc;
            const int colb = (nf * 16 + (l & 15)) * 2;
            *(_Float16*)(h1 + row * 256 + (colb ^ ((rloc & 7) << 4))) = (_Float16)elu1(acc[nf][r]);
        }
    __syncthreads();   // h1 visible

    i32x4 a1[4];
    #pragma unroll
    for (int ks = 0; ks < 4; ++ks) {
        const int row = rl16 + (l & 15);
        const int off = (ks * 64 + ((l >> 4) << 4)) ^ ((row & 7) << 4);
        a1[ks] = *(const i32x4*)(h1 + row * 256 + off);
    }

    #pragma unroll
    for (int nf = 0; nf < 8; ++nf) {
        float bv = g1b[nf * 16 + (l & 15)];
        acc[nf] = (f32x4){bv, bv, bv, bv};
    }
    #pragma unroll
    for (int ks = 0; ks < 4; ++ks)
        #pragma unroll
        for (int nf = 0; nf < 8; ++nf) {
            half8 b = *(const half8*)(sG1 + (size_t)(ks * 8 + nf) * 1024 + rdo);
            acc[nf] = __builtin_amdgcn_mfma_f32_16x16x32_f16(as_h8(a1[ks]), b, acc[nf], 0, 0, 0);
        }

    float pe[8][4];
    #pragma unroll
    for (int e = 0; e < 8; ++e)
        #pragma unroll
        for (int r = 0; r < 4; ++r) pe[e][r] = 0.f;
    #pragma unroll
    for (int nf = 0; nf < 8; ++nf) {
        float w_[8];
        #pragma unroll
        for (int e = 0; e < 8; ++e) w_[e] = wt_t[e * 128 + nf * 16 + (l & 15)];
        #pragma unroll
        for (int r = 0; r < 4; ++r) {
            float hv = elu1(acc[nf][r]);
            #pragma unroll
            for (int e = 0; e < 8; ++e) pe[e][r] = fmaf(hv, w_[e], pe[e][r]);
        }
    }
    #pragma unroll
    for (int off = 1; off < 16; off <<= 1)
        #pragma unroll
        for (int e = 0; e < 8; ++e)
            #pragma unroll
            for (int r = 0; r < 4; ++r) pe[e][r] += __shfl_xor(pe[e][r], off);

    if ((l & 15) == 0) {
        #pragma unroll
        for (int r = 0; r < 4; ++r) {
            float pv[8];
            float mx = -1e30f;
            #pragma unroll
            for (int e = 0; e < 8; ++e) { pv[e] = pe[e][r] + g2b[e]; mx = fmaxf(mx, pv[e]); }
            float s = 0.f;
            #pragma unroll
            for (int e = 0; e < 8; ++e) { pv[e] = expf(pv[e] - mx); s += pv[e]; }
            float inv = 1.0f / s;
            const int row = brow + rl16 + ((l >> 4) << 2) + r;
            #pragma unroll
            for (int e = 0; e < 8; ++e) coeff[(size_t)row * 8 + e] = pv[e] * inv;
        }
    }
}

// ---------- MoE layer: BK=64 thick phases, single 40KB buffer, 3 blocks/CU ----------
// Block 256 thr / 4 waves; tile 64 rows x 32 cols; wave owns experts 2w,2w+1.
// Phase p covers ks=2p,2p+1 (tail: one ks). Per phase: [vmcnt(0)+bar] ->
// 16 ds_read + 32 MFMA/wave -> [lgkmcnt(0)+bar] -> stage(p+1) (10 gloads/lane).
// Half the barrier events of BK=32; per-phase drain hidden by 2 other blocks.
template<int KS>
__global__ __launch_bounds__(256, 3) void k_moe_bk64(
    const _Float16* __restrict__ A, const _Float16* __restrict__ Bw,
    const float* __restrict__ bias,   // [8][256]
    const float* __restrict__ coeff,  // [B][8]
    _Float16* __restrict__ outX)
{
    constexpr int K  = KS * 32;
    constexpr int NP = (KS + 1) / 2;
    __shared__ __align__(16) char smem[43008];   // A 8KB | B 32KB | cf 2KB

    const int tid = threadIdx.x, wid = tid >> 6, l = tid & 63;
    const int brow = (blockIdx.x & 127) * 64;
    const int bn   = (blockIdx.x >> 7) * 32;

    float* cfl = (float*)(smem + 40960);         // [64][8]
    if (tid < 128) {
        f32x4 v = *(const f32x4*)&coeff[(size_t)(brow + (tid >> 1)) * 8 + (tid & 1) * 4];
        *(f32x4*)&cfl[tid * 4] = v;
    }

    const int swz = (((l & 3) ^ ((l >> 3) & 3)) << 3);
    const int rq  = l >> 2;
    const _Float16* sA = A + (size_t)(brow + wid * 16 + rq) * K + swz;
    const _Float16* sB2[2][2];
    #pragma unroll
    for (int e2 = 0; e2 < 2; ++e2)
        #pragma unroll
        for (int gg = 0; gg < 2; ++gg)
            sB2[e2][gg] = Bw + (size_t)((2 * wid + e2) * HID + bn + gg * 16 + rq) * K + swz;

    // buffer layout: A[h][unit] = h*4096 + u*1024 (u=0..3 rows);
    // B[h][e][gg] = 8192 + h*16384 + e*2048 + gg*1024
    auto stage = [&](int p) {
        const int ks0 = 2 * p;
        #pragma unroll
        for (int h = 0; h < 2; ++h) {
            if (ks0 + h >= KS) break;
            gload16(sA + (ks0 + h) * 32, smem + h * 4096 + wid * 1024);
            #pragma unroll
            for (int e2 = 0; e2 < 2; ++e2)
                #pragma unroll
                for (int gg = 0; gg < 2; ++gg)
                    gload16(sB2[e2][gg] + (ks0 + h) * 32,
                            smem + 8192 + h * 16384 + (2 * wid + e2) * 2048 + gg * 1024);
        }
    };

    const int rdo = ((l & 15) << 6) + (((l >> 4) ^ ((l >> 1) & 3)) << 4);
    f32x4 acc[2][4][2];
    #pragma unroll
    for (int e2 = 0; e2 < 2; ++e2)
        #pragma unroll
        for (int mf = 0; mf < 4; ++mf)
            #pragma unroll
            for (int nf = 0; nf < 2; ++nf) acc[e2][mf][nf] = (f32x4){0.f, 0.f, 0.f, 0.f};

    stage(0);
    __syncthreads();   // drains stage(0) + cf

    for (int p = 0; p < NP; ++p) {
        if (p > 0) {
            asm volatile("s_waitcnt vmcnt(0)" ::: "memory");   // stage(p) landed
            __builtin_amdgcn_s_barrier();
            __builtin_amdgcn_sched_barrier(0);
        }
        #pragma unroll
        for (int h = 0; h < 2; ++h) {
            if (2 * p + h >= KS) break;
            half8 af[4], b0[2], b1[2];
            #pragma unroll
            for (int mf = 0; mf < 4; ++mf)
                af[mf] = *(const half8*)(smem + h * 4096 + mf * 1024 + rdo);
            #pragma unroll
            for (int e2 = 0; e2 < 2; ++e2) {
                const char* be = smem + 8192 + h * 16384 + (2 * wid + e2) * 2048;
                b0[e2] = *(const half8*)(be + rdo);
                b1[e2] = *(const half8*)(be + 1024 + rdo);
            }
            __builtin_amdgcn_s_setprio(1);
            #pragma unroll
            for (int e2 = 0; e2 < 2; ++e2)
                #pragma unroll
                for (int mf = 0; mf < 4; ++mf) {
                    acc[e2][mf][0] = __builtin_amdgcn_mfma_f32_16x16x32_f16(af[mf], b0[e2], acc[e2][mf][0], 0, 0, 0);
                    acc[e2][mf][1] = __builtin_amdgcn_mfma_f32_16x16x32_f16(af[mf], b1[e2], acc[e2][mf][1], 0, 0, 0);
                }
            __builtin_amdgcn_s_setprio(0);
        }
        asm volatile("s_waitcnt lgkmcnt(0)" ::: "memory");     // all reads retired
        __builtin_amdgcn_sched_barrier(0);
        __builtin_amdgcn_s_barrier();                          // safe to overwrite
        if (p + 1 < NP) stage(p + 1);
    }

    // ---- epilogue: (acc+bias)*cf per wave-expert pair, cross-wave reduce ----
    const int e0 = 2 * wid, e1 = 2 * wid + 1;
    float bv0[2], bv1[2];
    #pragma unroll
    for (int nf = 0; nf < 2; ++nf) {
        bv0[nf] = bias[e0 * HID + bn + nf * 16 + (l & 15)];
        bv1[nf] = bias[e1 * HID + bn + nf * 16 + (l & 15)];
    }
    float* red = (float*)smem;                        // [4][64][36] overlays stage buf
    #pragma unroll
    for (int mf = 0; mf < 4; ++mf) {
        const int rb = mf * 16 + ((l >> 4) << 2);
        #pragma unroll
        for (int r = 0; r < 4; ++r) {
            float c0 = cfl[(rb + r) * 8 + e0];
            float c1 = cfl[(rb + r) * 8 + e1];
            #pragma unroll
            for (int nf = 0; nf < 2; ++nf) {
                float s = (acc[0][mf][nf][r] + bv0[nf]) * c0
                        + (acc[1][mf][nf][r] + bv1[nf]) * c1;
                red[wid * 2304 + (rb + r) * 36 + nf * 16 + (l & 15)] = s;
            }
        }
    }
    __syncthreads();

    const int row = tid >> 2, c0_ = (tid & 3) * 8;
    f32x4 s0 = {0.f, 0.f, 0.f, 0.f}, s1 = {0.f, 0.f, 0.f, 0.f};
    #pragma unroll
    for (int w = 0; w < 4; ++w) {
        s0 += *(const f32x4*)&red[w * 2304 + row * 36 + c0_];
        s1 += *(const f32x4*)&red[w * 2304 + row * 36 + c0_ + 4];
    }
    _Float16 hh[8];
    #pragma unroll
    for (int j = 0; j < 4; ++j) {
        hh[j]     = (_Float16)elu1(s0[j]);
        hh[4 + j] = (_Float16)elu1(s1[j]);
    }
    size_t o = (size_t)(brow + row) * INTER + 32 + bn + c0_;
    *(half8*)&outX[o] = *(const half8*)hh;
}

// ---------- fused final layer + mix: ks-pipelined staging via counted vmcnt ----------
__global__ __launch_bounds__(128, 2) void k_final(
    const _Float16* __restrict__ X2, const _Float16* __restrict__ T2,
    const float* __restrict__ b2, const float* __restrict__ cf,
    float* __restrict__ out)
{
    __shared__ __align__(16) char smem[73728];   // 9 ks x 8 g x 1KB
    const int tid = threadIdx.x, wid = tid >> 6, l = tid & 63;
    const int brow = blockIdx.x * 32;

    const _Float16* Ar = X2 + (size_t)(brow + wid * 16 + (l & 15)) * INTER + (l >> 4) * 8;
    i32x4 a_[9];
    #pragma unroll
    for (int ks = 0; ks < 9; ++ks) a_[ks] = *(const i32x4*)(Ar + ks * 32);

    const int swz = (((l & 3) ^ ((l >> 3) & 3)) << 3);
    const int rq  = l >> 2;
    #pragma unroll
    for (int p = 0; p < 72; ++p) {
        if ((p & 1) != wid) continue;
        const int ks = p / 8, gg = p % 8;
        gload16(T2 + (size_t)(gg * 16 + rq) * INTER + ks * 32 + swz, smem + p * 1024);
    }

    const int rdo = ((l & 15) << 6) + (((l >> 4) ^ ((l >> 1) & 3)) << 4);
    f32x4 acc[8];
    #pragma unroll
    for (int nf = 0; nf < 8; ++nf) {
        float bv = b2[nf * 16 + (l & 15)];
        acc[nf] = (f32x4){bv, bv, bv, bv};
    }
    #pragma unroll
    for (int ks = 0; ks < 9; ++ks) {
        switch (ks) {
            case 0: asm volatile("s_waitcnt vmcnt(32)" ::: "memory"); break;
            case 1: asm volatile("s_waitcnt vmcnt(28)" ::: "memory"); break;
            case 2: asm volatile("s_waitcnt vmcnt(24)" ::: "memory"); break;
            case 3: asm volatile("s_waitcnt vmcnt(20)" ::: "memory"); break;
            case 4: asm volatile("s_waitcnt vmcnt(16)" ::: "memory"); break;
            case 5: asm volatile("s_waitcnt vmcnt(12)" ::: "memory"); break;
            case 6: asm volatile("s_waitcnt vmcnt(8)"  ::: "memory"); break;
            case 7: asm volatile("s_waitcnt vmcnt(4)"  ::: "memory"); break;
            default: asm volatile("s_waitcnt vmcnt(0)" ::: "memory"); break;
        }
        __builtin_amdgcn_s_barrier();
        __builtin_amdgcn_sched_barrier(0);
        if (ks == 0) {
            #pragma unroll
            for (int k2 = 0; k2 < 9; ++k2) asm volatile("" : "+v"(a_[k2]));
        }
        #pragma unroll
        for (int nf = 0; nf < 8; ++nf) {
            half8 b = *(const half8*)(smem + (size_t)(ks * 8 + nf) * 1024 + rdo);
            acc[nf] = __builtin_amdgcn_mfma_f32_16x16x32_f16(as_h8(a_[ks]), b, acc[nf], 0, 0, 0);
        }
    }

    #pragma unroll
    for (int r = 0; r < 4; ++r) {
        const int row = brow + wid * 16 + ((l >> 4) << 2) + r;
        const float* cr = cf + (size_t)row * 8;
        float s = 0.f;
        #pragma unroll
        for (int e = 0; e < 8; ++e) s = fmaf(cr[e], acc[e][r], s);
        out[(size_t)row * ACTD + (l & 15)] = s;
    }
}

extern "C" void kernel_launch(void* const* d_in, const int* in_sizes, int n_in,
                              void* d_out, int out_size, void* d_ws, size_t ws_size,
                              hipStream_t stream)
{
    (void)in_sizes; (void)n_in; (void)out_size; (void)ws_size;
    const float* z   = (const float*)d_in[0];
    const float* c   = (const float*)d_in[1];
    const float* w0  = (const float*)d_in[2];
    const float* b0  = (const float*)d_in[3];
    const float* w1  = (const float*)d_in[4];
    const float* b1  = (const float*)d_in[5];
    const float* w2  = (const float*)d_in[6];
    const float* b2  = (const float*)d_in[7];
    const float* g0w = (const float*)d_in[8];
    const float* g0b = (const float*)d_in[9];
    const float* g1w = (const float*)d_in[10];
    const float* g1b = (const float*)d_in[11];
    const float* g2w = (const float*)d_in[12];
    const float* g2b = (const float*)d_in[13];
    const float* lng = (const float*)d_in[14];
    const float* lnb = (const float*)d_in[15];
    float* out = (float*)d_out;

    char* p = (char*)d_ws;
    auto alloc = [&](size_t n) { char* r = p; p += (n + 255) & ~(size_t)255; return r; };
    _Float16* X0  = (_Float16*)alloc((size_t)B_ * IN0 * 2);
    _Float16* X1  = (_Float16*)alloc((size_t)B_ * INTER * 2);
    _Float16* X2  = (_Float16*)alloc((size_t)B_ * INTER * 2);
    float* cf  = (float*)alloc((size_t)B_ * NE * 4);
    _Float16* T0  = (_Float16*)alloc((size_t)NE * IN0 * HID * 2);
    _Float16* T1  = (_Float16*)alloc((size_t)NE * INTER * HID * 2);
    _Float16* T2  = (_Float16*)alloc((size_t)NE * INTER * ACTD * 2);
    _Float16* G0T = (_Float16*)alloc((size_t)IN0 * GH * 2);
    _Float16* G1T = (_Float16*)alloc((size_t)GH * GH * 2);

    k_prep_ln<<<dim3(484 + B_ / 4), dim3(256), 0, stream>>>(
        w0, w1, w2, g0w, g1w, z, c, lng, lnb,
        T0, T1, T2, G0T, G1T, X0, X1, X2);

    // fused gate MLP -> coeff
    k_gate_fused<<<dim3(256), dim3(128), 0, stream>>>(
        X0, G0T, G1T, g0b, g1b, g2w, g2b, cf);

    // expert layers: BK=64 thick phases, single buffer, 3 blocks/CU
    k_moe_bk64<5><<<dim3(1024), dim3(256), 0, stream>>>(X0, T0, b0, cf, X1);
    k_moe_bk64<9><<<dim3(1024), dim3(256), 0, stream>>>(X1, T1, b1, cf, X2);

    // fused final layer + mix
    k_final<<<dim3(256), dim3(128), 0, stream>>>(X2, T2, b2, cf, out);
}

// Round 18
// 65.239 us; speedup vs baseline: 1.0513x; 1.0513x over previous
//
#include <hip/hip_runtime.h>
#include <math.h>

#define B_     8192
#define LATENT 32
#define CIN    128
#define HID    256
#define ACTD   16
#define NE     8
#define GH     128
#define IN0    160   // LATENT + CIN
#define INTER  288   // HID + LATENT

typedef __attribute__((ext_vector_type(8))) _Float16 half8;
typedef __attribute__((ext_vector_type(4))) float    f32x4;
typedef __attribute__((ext_vector_type(4))) int      i32x4;

__device__ __forceinline__ float elu1(float x) { return x > 0.0f ? x : expm1f(x); }

__device__ __forceinline__ void gload16(const void* g, const char* lds) {
    __builtin_amdgcn_global_load_lds((const __attribute__((address_space(1))) void*)g,
                                     (__attribute__((address_space(3))) void*)lds, 16, 0, 0);
}
__device__ __forceinline__ half8 as_h8(i32x4 v) {
    union U { i32x4 a; half8 b; } u; u.a = v; return u.b;
}

// ---------- fused prep (weight transpose+fp16) and LayerNorm/concat ----------
__global__ __launch_bounds__(256) void k_prep_ln(
    const float* __restrict__ w0, const float* __restrict__ w1, const float* __restrict__ w2,
    const float* __restrict__ g0w, const float* __restrict__ g1w,
    const float* __restrict__ z, const float* __restrict__ c,
    const float* __restrict__ g, const float* __restrict__ bt,
    _Float16* __restrict__ T0, _Float16* __restrict__ T1, _Float16* __restrict__ T2,
    _Float16* __restrict__ G0, _Float16* __restrict__ G1,
    _Float16* __restrict__ X0, _Float16* __restrict__ X1, _Float16* __restrict__ X2)
{
    if (blockIdx.x < 484) {
        int gq = blockIdx.x * 256 + threadIdx.x;
        const float* src; int stride; size_t dst; _Float16* H;
        if (gq < 40960) {                      // T0: [8][160][256] -> [8*256][160]
            int e = gq / 5120, r = gq % 5120, o = r / 20, i0 = (r % 20) * 8;
            src = w0 + ((size_t)e * 160 + i0) * 256 + o; stride = 256;
            dst = ((size_t)e * 256 + o) * 160 + i0; H = T0;
        } else if (gq < 114688) {              // T1
            int t = gq - 40960;
            int e = t / 9216, r = t % 9216, o = r / 36, i0 = (r % 36) * 8;
            src = w1 + ((size_t)e * 288 + i0) * 256 + o; stride = 256;
            dst = ((size_t)e * 256 + o) * 288 + i0; H = T1;
        } else if (gq < 119296) {              // T2
            int t = gq - 114688;
            int e = t / 576, r = t % 576, o = r / 36, i0 = (r % 36) * 8;
            src = w2 + ((size_t)e * 288 + i0) * 16 + o; stride = 16;
            dst = ((size_t)e * 16 + o) * 288 + i0; H = T2;
        } else if (gq < 121856) {              // G0
            int t = gq - 119296;
            int o = t / 20, i0 = (t % 20) * 8;
            src = g0w + (size_t)i0 * 128 + o; stride = 128;
            dst = (size_t)o * 160 + i0; H = G0;
        } else if (gq < 123904) {              // G1
            int t = gq - 121856;
            int o = t / 16, i0 = (t % 16) * 8;
            src = g1w + (size_t)i0 * 128 + o; stride = 128;
            dst = (size_t)o * 128 + i0; H = G1;
        } else return;
        _Float16 hh[8];
        #pragma unroll
        for (int j = 0; j < 8; ++j) hh[j] = (_Float16)src[(size_t)j * stride];
        *(half8*)&H[dst] = *(const half8*)hh;
        return;
    }
    // ---- LayerNorm branch ----
    int gid = (blockIdx.x - 484) * 256 + threadIdx.x;
    int row = gid >> 6;
    int l = threadIdx.x & 63;
    const float* cr = c + (size_t)row * CIN;
    float v0 = cr[l], v1 = cr[l + 64];
    float s = v0 + v1;
    #pragma unroll
    for (int o = 32; o; o >>= 1) s += __shfl_xor(s, o);
    float mean = s * (1.0f / 128.0f);
    float d0 = v0 - mean, d1 = v1 - mean;
    float q = d0 * d0 + d1 * d1;
    #pragma unroll
    for (int o = 32; o; o >>= 1) q += __shfl_xor(q, o);
    float rstd = rsqrtf(q * (1.0f / 128.0f) + 1e-5f);
    float y0 = d0 * rstd * g[l] + bt[l];
    float y1 = d1 * rstd * g[l + 64] + bt[l + 64];
    size_t r0 = (size_t)row * IN0;
    X0[r0 + 32 + l] = (_Float16)y0;
    X0[r0 + 96 + l] = (_Float16)y1;
    if (l < LATENT) {
        _Float16 zv = (_Float16)z[(size_t)row * LATENT + l];
        X0[r0 + l] = zv;
        size_t r1 = (size_t)row * INTER;
        X1[r1 + l] = zv;
        X2[r1 + l] = zv;
    }
}

// ---------- fused gate MLP: both weight stages issued up-front (no mid stall) ----------
__global__ __launch_bounds__(128, 2) void k_gate_fused(
    const _Float16* __restrict__ X0, const _Float16* __restrict__ G0T,
    const _Float16* __restrict__ G1T,
    const float* __restrict__ g0b, const float* __restrict__ g1b,
    const float* __restrict__ g2w, const float* __restrict__ g2b,
    float* __restrict__ coeff)
{
    __shared__ __align__(16) char smem[86016];   // G0 40KB | G1 32KB | h1 8KB | wt_t 4KB
    const int tid = threadIdx.x, wid = tid >> 6, l = tid & 63;
    const int brow = blockIdx.x * 32;
    const int rl16 = wid * 16;

    char* sG1  = smem + 40960;
    char* h1   = smem + 73728;                   // [32 rows][256 B]
    float* wt_t = (float*)(smem + 81920);        // [8][128] f32

    const int swz = (((l & 3) ^ ((l >> 3) & 3)) << 3);
    const int rq  = l >> 2;
    const int rdo = ((l & 15) << 6) + (((l >> 4) ^ ((l >> 1) & 3)) << 4);

    #pragma unroll
    for (int p = 0; p < 40; ++p) {
        if ((p & 1) != wid) continue;
        const int ks = p / 8, gg = p % 8;
        gload16(G0T + (size_t)(gg * 16 + rq) * IN0 + ks * 32 + swz, smem + p * 1024);
    }
    #pragma unroll
    for (int p = 0; p < 32; ++p) {
        if ((p & 1) != wid) continue;
        const int ks = p / 8, gg = p % 8;
        gload16(G1T + (size_t)(gg * 16 + rq) * GH + ks * 32 + swz, sG1 + p * 1024);
    }
    const _Float16* Ar0 = X0 + (size_t)(brow + rl16 + (l & 15)) * IN0 + (l >> 4) * 8;
    i32x4 a0[5];
    #pragma unroll
    for (int ks = 0; ks < 5; ++ks) a0[ks] = *(const i32x4*)(Ar0 + ks * 32);
    for (int idx = tid; idx < 1024; idx += 128)
        wt_t[(idx & 7) * 128 + (idx >> 3)] = g2w[(idx >> 3) * 8 + (idx & 7)];
    __syncthreads();   // full drain: everything staged

    f32x4 acc[8];
    #pragma unroll
    for (int nf = 0; nf < 8; ++nf) {
        float bv = g0b[nf * 16 + (l & 15)];
        acc[nf] = (f32x4){bv, bv, bv, bv};
    }
    #pragma unroll
    for (int ks = 0; ks < 5; ++ks)
        #pragma unroll
        for (int nf = 0; nf < 8; ++nf) {
            half8 b = *(const half8*)(smem + (size_t)(ks * 8 + nf) * 1024 + rdo);
            acc[nf] = __builtin_amdgcn_mfma_f32_16x16x32_f16(as_h8(a0[ks]), b, acc[nf], 0, 0, 0);
        }

    #pragma unroll
    for (int nf = 0; nf < 8; ++nf)
        #pragma unroll
        for (int r = 0; r < 4; ++r) {
            const int rloc = ((l >> 4) << 2) + r;
            const int row = rl16 + rloc;
            const int colb = (nf * 16 + (l & 15)) * 2;
            *(_Float16*)(h1 + row * 256 + (colb ^ ((rloc & 7) << 4))) = (_Float16)elu1(acc[nf][r]);
        }
    __syncthreads();   // h1 visible

    i32x4 a1[4];
    #pragma unroll
    for (int ks = 0; ks < 4; ++ks) {
        const int row = rl16 + (l & 15);
        const int off = (ks * 64 + ((l >> 4) << 4)) ^ ((row & 7) << 4);
        a1[ks] = *(const i32x4*)(h1 + row * 256 + off);
    }

    #pragma unroll
    for (int nf = 0; nf < 8; ++nf) {
        float bv = g1b[nf * 16 + (l & 15)];
        acc[nf] = (f32x4){bv, bv, bv, bv};
    }
    #pragma unroll
    for (int ks = 0; ks < 4; ++ks)
        #pragma unroll
        for (int nf = 0; nf < 8; ++nf) {
            half8 b = *(const half8*)(sG1 + (size_t)(ks * 8 + nf) * 1024 + rdo);
            acc[nf] = __builtin_amdgcn_mfma_f32_16x16x32_f16(as_h8(a1[ks]), b, acc[nf], 0, 0, 0);
        }

    float pe[8][4];
    #pragma unroll
    for (int e = 0; e < 8; ++e)
        #pragma unroll
        for (int r = 0; r < 4; ++r) pe[e][r] = 0.f;
    #pragma unroll
    for (int nf = 0; nf < 8; ++nf) {
        float w_[8];
        #pragma unroll
        for (int e = 0; e < 8; ++e) w_[e] = wt_t[e * 128 + nf * 16 + (l & 15)];
        #pragma unroll
        for (int r = 0; r < 4; ++r) {
            float hv = elu1(acc[nf][r]);
            #pragma unroll
            for (int e = 0; e < 8; ++e) pe[e][r] = fmaf(hv, w_[e], pe[e][r]);
        }
    }
    #pragma unroll
    for (int off = 1; off < 16; off <<= 1)
        #pragma unroll
        for (int e = 0; e < 8; ++e)
            #pragma unroll
            for (int r = 0; r < 4; ++r) pe[e][r] += __shfl_xor(pe[e][r], off);

    if ((l & 15) == 0) {
        #pragma unroll
        for (int r = 0; r < 4; ++r) {
            float pv[8];
            float mx = -1e30f;
            #pragma unroll
            for (int e = 0; e < 8; ++e) { pv[e] = pe[e][r] + g2b[e]; mx = fmaxf(mx, pv[e]); }
            float s = 0.f;
            #pragma unroll
            for (int e = 0; e < 8; ++e) { pv[e] = expf(pv[e] - mx); s += pv[e]; }
            float inv = 1.0f / s;
            const int row = brow + rl16 + ((l >> 4) << 2) + r;
            #pragma unroll
            for (int e = 0; e < 8; ++e) coeff[(size_t)row * 8 + e] = pv[e] * inv;
        }
    }
}

// ---------- MoE layer: fp16, expert-parallel waves, double-buffered, 3 blocks/CU ----------
// (r14 best-measured configuration: compute -> lgkmcnt+barrier -> refill freed
// buf -> counted vmcnt(5)+barrier; robust high-bit bn mapping; cfl in LDS.)
template<int KS>
__global__ __launch_bounds__(256, 3) void k_moe_epar(
    const _Float16* __restrict__ A, const _Float16* __restrict__ Bw,
    const float* __restrict__ bias,   // [8][256]
    const float* __restrict__ coeff,  // [B][8]
    _Float16* __restrict__ outX)
{
    constexpr int K = KS * 32;
    __shared__ __align__(16) char smem[43008];   // 2 bufs x 20480 + cf 2048

    const int tid = threadIdx.x, wid = tid >> 6, l = tid & 63;
    // robust mapping: any 128-consecutive-bid window shares one bn slice
    const int brow = (blockIdx.x & 127) * 64;
    const int bn   = (blockIdx.x >> 7) * 32;

    float* cfl = (float*)(smem + 40960);         // [64][8]
    if (tid < 128) {
        f32x4 v = *(const f32x4*)&coeff[(size_t)(brow + (tid >> 1)) * 8 + (tid & 1) * 4];
        *(f32x4*)&cfl[tid * 4] = v;
    }

    const int swz = (((l & 3) ^ ((l >> 3) & 3)) << 3);
    const int rq  = l >> 2;
    const _Float16* sA = A + (size_t)(brow + wid * 16 + rq) * K + swz;
    const _Float16* sB2[2][2];
    #pragma unroll
    for (int e2 = 0; e2 < 2; ++e2)
        #pragma unroll
        for (int gg = 0; gg < 2; ++gg)
            sB2[e2][gg] = Bw + (size_t)((2 * wid + e2) * HID + bn + gg * 16 + rq) * K + swz;

    auto stage = [&](int bi, int k0) {   // 5 gload16 per lane
        char* buf = smem + bi * 20480;
        gload16(sA + k0, buf + wid * 1024);
        #pragma unroll
        for (int e2 = 0; e2 < 2; ++e2)
            #pragma unroll
            for (int gg = 0; gg < 2; ++gg)
                gload16(sB2[e2][gg] + k0,
                        buf + 4096 + (2 * wid + e2) * 2048 + gg * 1024);
    };

    const int rdo = ((l & 15) << 6) + (((l >> 4) ^ ((l >> 1) & 3)) << 4);
    f32x4 acc[2][4][2];
    #pragma unroll
    for (int e2 = 0; e2 < 2; ++e2)
        #pragma unroll
        for (int mf = 0; mf < 4; ++mf)
            #pragma unroll
            for (int nf = 0; nf < 2; ++nf) acc[e2][mf][nf] = (f32x4){0.f, 0.f, 0.f, 0.f};

    stage(0, 0);
    if (KS > 1) stage(1, 32);
    __syncthreads();   // full drain: both bufs + cf

    for (int t = 0; t < KS; ++t) {
        const char* buf = smem + (t & 1) * 20480;
        half8 af[4];
        #pragma unroll
        for (int mf = 0; mf < 4; ++mf)
            af[mf] = *(const half8*)(buf + mf * 1024 + rdo);
        __builtin_amdgcn_s_setprio(1);
        #pragma unroll
        for (int e2 = 0; e2 < 2; ++e2) {
            const char* be = buf + 4096 + (2 * wid + e2) * 2048;
            half8 b0 = *(const half8*)(be + rdo);
            half8 b1 = *(const half8*)(be + 1024 + rdo);
            #pragma unroll
            for (int mf = 0; mf < 4; ++mf) {
                acc[e2][mf][0] = __builtin_amdgcn_mfma_f32_16x16x32_f16(af[mf], b0, acc[e2][mf][0], 0, 0, 0);
                acc[e2][mf][1] = __builtin_amdgcn_mfma_f32_16x16x32_f16(af[mf], b1, acc[e2][mf][1], 0, 0, 0);
            }
        }
        __builtin_amdgcn_s_setprio(0);
        asm volatile("s_waitcnt lgkmcnt(0)" ::: "memory");
        __builtin_amdgcn_sched_barrier(0);
        __builtin_amdgcn_s_barrier();                 // reads of buf(t) retired
        if (t + 2 < KS) stage(t & 1, (t + 2) * 32);   // refill the freed buf
        if (t + 1 < KS) {
            if (t + 2 < KS) { asm volatile("s_waitcnt vmcnt(5)" ::: "memory"); }
            else            { asm volatile("s_waitcnt vmcnt(0)" ::: "memory"); }
            __builtin_amdgcn_s_barrier();             // buf(t+1) ready
            __builtin_amdgcn_sched_barrier(0);
        }
    }

    // ---- epilogue: (acc+bias)*cf per wave-expert pair, cross-wave reduce ----
    const int e0 = 2 * wid, e1 = 2 * wid + 1;
    float bv0[2], bv1[2];
    #pragma unroll
    for (int nf = 0; nf < 2; ++nf) {
        bv0[nf] = bias[e0 * HID + bn + nf * 16 + (l & 15)];
        bv1[nf] = bias[e1 * HID + bn + nf * 16 + (l & 15)];
    }
    float* red = (float*)smem;                        // [4][64][36]
    #pragma unroll
    for (int mf = 0; mf < 4; ++mf) {
        const int rb = mf * 16 + ((l >> 4) << 2);
        #pragma unroll
        for (int r = 0; r < 4; ++r) {
            float c0 = cfl[(rb + r) * 8 + e0];
            float c1 = cfl[(rb + r) * 8 + e1];
            #pragma unroll
            for (int nf = 0; nf < 2; ++nf) {
                float s = (acc[0][mf][nf][r] + bv0[nf]) * c0
                        + (acc[1][mf][nf][r] + bv1[nf]) * c1;
                red[wid * 2304 + (rb + r) * 36 + nf * 16 + (l & 15)] = s;
            }
        }
    }
    __syncthreads();

    const int row = tid >> 2, c0_ = (tid & 3) * 8;
    f32x4 s0 = {0.f, 0.f, 0.f, 0.f}, s1 = {0.f, 0.f, 0.f, 0.f};
    #pragma unroll
    for (int w = 0; w < 4; ++w) {
        s0 += *(const f32x4*)&red[w * 2304 + row * 36 + c0_];
        s1 += *(const f32x4*)&red[w * 2304 + row * 36 + c0_ + 4];
    }
    _Float16 hh[8];
    #pragma unroll
    for (int j = 0; j < 4; ++j) {
        hh[j]     = (_Float16)elu1(s0[j]);
        hh[4 + j] = (_Float16)elu1(s1[j]);
    }
    size_t o = (size_t)(brow + row) * INTER + 32 + bn + c0_;
    *(half8*)&outX[o] = *(const half8*)hh;
}

// ---------- fused final layer + mix: ks-pipelined staging via counted vmcnt ----------
__global__ __launch_bounds__(128, 2) void k_final(
    const _Float16* __restrict__ X2, const _Float16* __restrict__ T2,
    const float* __restrict__ b2, const float* __restrict__ cf,
    float* __restrict__ out)
{
    __shared__ __align__(16) char smem[73728];   // 9 ks x 8 g x 1KB
    const int tid = threadIdx.x, wid = tid >> 6, l = tid & 63;
    const int brow = blockIdx.x * 32;

    const _Float16* Ar = X2 + (size_t)(brow + wid * 16 + (l & 15)) * INTER + (l >> 4) * 8;
    i32x4 a_[9];
    #pragma unroll
    for (int ks = 0; ks < 9; ++ks) a_[ks] = *(const i32x4*)(Ar + ks * 32);

    const int swz = (((l & 3) ^ ((l >> 3) & 3)) << 3);
    const int rq  = l >> 2;
    #pragma unroll
    for (int p = 0; p < 72; ++p) {
        if ((p & 1) != wid) continue;
        const int ks = p / 8, gg = p % 8;
        gload16(T2 + (size_t)(gg * 16 + rq) * INTER + ks * 32 + swz, smem + p * 1024);
    }

    const int rdo = ((l & 15) << 6) + (((l >> 4) ^ ((l >> 1) & 3)) << 4);
    f32x4 acc[8];
    #pragma unroll
    for (int nf = 0; nf < 8; ++nf) {
        float bv = b2[nf * 16 + (l & 15)];
        acc[nf] = (f32x4){bv, bv, bv, bv};
    }
    #pragma unroll
    for (int ks = 0; ks < 9; ++ks) {
        switch (ks) {
            case 0: asm volatile("s_waitcnt vmcnt(32)" ::: "memory"); break;
            case 1: asm volatile("s_waitcnt vmcnt(28)" ::: "memory"); break;
            case 2: asm volatile("s_waitcnt vmcnt(24)" ::: "memory"); break;
            case 3: asm volatile("s_waitcnt vmcnt(20)" ::: "memory"); break;
            case 4: asm volatile("s_waitcnt vmcnt(16)" ::: "memory"); break;
            case 5: asm volatile("s_waitcnt vmcnt(12)" ::: "memory"); break;
            case 6: asm volatile("s_waitcnt vmcnt(8)"  ::: "memory"); break;
            case 7: asm volatile("s_waitcnt vmcnt(4)"  ::: "memory"); break;
            default: asm volatile("s_waitcnt vmcnt(0)" ::: "memory"); break;
        }
        __builtin_amdgcn_s_barrier();
        __builtin_amdgcn_sched_barrier(0);
        if (ks == 0) {
            #pragma unroll
            for (int k2 = 0; k2 < 9; ++k2) asm volatile("" : "+v"(a_[k2]));
        }
        #pragma unroll
        for (int nf = 0; nf < 8; ++nf) {
            half8 b = *(const half8*)(smem + (size_t)(ks * 8 + nf) * 1024 + rdo);
            acc[nf] = __builtin_amdgcn_mfma_f32_16x16x32_f16(as_h8(a_[ks]), b, acc[nf], 0, 0, 0);
        }
    }

    #pragma unroll
    for (int r = 0; r < 4; ++r) {
        const int row = brow + wid * 16 + ((l >> 4) << 2) + r;
        const float* cr = cf + (size_t)row * 8;
        float s = 0.f;
        #pragma unroll
        for (int e = 0; e < 8; ++e) s = fmaf(cr[e], acc[e][r], s);
        out[(size_t)row * ACTD + (l & 15)] = s;
    }
}

extern "C" void kernel_launch(void* const* d_in, const int* in_sizes, int n_in,
                              void* d_out, int out_size, void* d_ws, size_t ws_size,
                              hipStream_t stream)
{
    (void)in_sizes; (void)n_in; (void)out_size; (void)ws_size;
    const float* z   = (const float*)d_in[0];
    const float* c   = (const float*)d_in[1];
    const float* w0  = (const float*)d_in[2];
    const float* b0  = (const float*)d_in[3];
    const float* w1  = (const float*)d_in[4];
    const float* b1  = (const float*)d_in[5];
    const float* w2  = (const float*)d_in[6];
    const float* b2  = (const float*)d_in[7];
    const float* g0w = (const float*)d_in[8];
    const float* g0b = (const float*)d_in[9];
    const float* g1w = (const float*)d_in[10];
    const float* g1b = (const float*)d_in[11];
    const float* g2w = (const float*)d_in[12];
    const float* g2b = (const float*)d_in[13];
    const float* lng = (const float*)d_in[14];
    const float* lnb = (const float*)d_in[15];
    float* out = (float*)d_out;

    char* p = (char*)d_ws;
    auto alloc = [&](size_t n) { char* r = p; p += (n + 255) & ~(size_t)255; return r; };
    _Float16* X0  = (_Float16*)alloc((size_t)B_ * IN0 * 2);
    _Float16* X1  = (_Float16*)alloc((size_t)B_ * INTER * 2);
    _Float16* X2  = (_Float16*)alloc((size_t)B_ * INTER * 2);
    float* cf  = (float*)alloc((size_t)B_ * NE * 4);
    _Float16* T0  = (_Float16*)alloc((size_t)NE * IN0 * HID * 2);
    _Float16* T1  = (_Float16*)alloc((size_t)NE * INTER * HID * 2);
    _Float16* T2  = (_Float16*)alloc((size_t)NE * INTER * ACTD * 2);
    _Float16* G0T = (_Float16*)alloc((size_t)IN0 * GH * 2);
    _Float16* G1T = (_Float16*)alloc((size_t)GH * GH * 2);

    k_prep_ln<<<dim3(484 + B_ / 4), dim3(256), 0, stream>>>(
        w0, w1, w2, g0w, g1w, z, c, lng, lnb,
        T0, T1, T2, G0T, G1T, X0, X1, X2);

    // fused gate MLP -> coeff
    k_gate_fused<<<dim3(256), dim3(128), 0, stream>>>(
        X0, G0T, G1T, g0b, g1b, g2w, g2b, cf);

    // expert layers: double-buffered, 3 blocks/CU (best-measured config)
    k_moe_epar<5><<<dim3(1024), dim3(256), 0, stream>>>(X0, T0, b0, cf, X1);
    k_moe_epar<9><<<dim3(1024), dim3(256), 0, stream>>>(X1, T1, b1, cf, X2);

    // fused final layer + mix
    k_final<<<dim3(256), dim3(128), 0, stream>>>(X2, T2, b2, cf, out);
}